// Round 1
// baseline (234.882 us; speedup 1.0000x reference)
//
#include <hip/hip_runtime.h>
#include <math.h>

#define BB 64
#define MM 128
#define DDIM 2048
#define KK 32
#define NFR (BB*MM)              // 8192
#define OUTROW (DDIM + KK*DDIM)  // 67584

// ---------------------------------------------------------------------------
// K1: partial dots (logits) + partial sum-of-squares per frame, d-chunked.
// grid (32 frame-groups, 8 d-chunks) x 256 threads. lane == frame in compute.
// x staged through LDS transpose so global reads are coalesced while compute
// reads are per-lane rows (stride 33 -> 2-way bank alias, free).
// W addresses are wave-uniform -> compiler should emit s_load (or broadcast).
// ---------------------------------------------------------------------------
__global__ __launch_bounds__(256) void k_dots(const float* __restrict__ x,
        const int* __restrict__ lengths, const float* __restrict__ W,
        float* __restrict__ part_dots, float* __restrict__ part_ssq) {
  __shared__ float xs[256][33];
  const int t  = threadIdx.x;
  const int fg = blockIdx.x;      // 0..31  (256 frames each)
  const int dc = blockIdx.y;      // 0..7   (256 d each)
  const int g0 = fg * 256;
  const int d0 = dc * 256;

  const int fr_st = t >> 3;       // staging frame sub-index 0..31
  const int dq    = t & 7;        // staging float4 column 0..7

  bool va[8];
  #pragma unroll
  for (int i = 0; i < 8; ++i) {
    int g = g0 + i*32 + fr_st;
    va[i] = (g & (MM-1)) < lengths[g >> 7];
  }

  float acc[KK];
  #pragma unroll
  for (int k = 0; k < KK; ++k) acc[k] = 0.f;
  float ssq = 0.f;

  for (int s = 0; s < 8; ++s) {
    const int dbase = d0 + s*32;
    // stage 256 frames x 32 d (zero-fill masked frames: saves HBM, stays finite)
    #pragma unroll
    for (int i = 0; i < 8; ++i) {
      int fr = i*32 + fr_st;
      int g  = g0 + fr;
      float4 v = make_float4(0.f, 0.f, 0.f, 0.f);
      if (va[i]) v = *(const float4*)(x + (size_t)g*DDIM + dbase + dq*4);
      xs[fr][dq*4+0] = v.x; xs[fr][dq*4+1] = v.y;
      xs[fr][dq*4+2] = v.z; xs[fr][dq*4+3] = v.w;
    }
    __syncthreads();

    const float* wp = W + dbase;   // wave-uniform base
    for (int dd = 0; dd < 32; ++dd) {
      float xv = xs[t][dd];
      ssq = fmaf(xv, xv, ssq);
      #pragma unroll
      for (int k = 0; k < KK; ++k)
        acc[k] = fmaf(wp[(size_t)k*DDIM + dd], xv, acc[k]);
    }
    __syncthreads();
  }

  const int g = g0 + t;
  float* po = part_dots + ((size_t)dc*NFR + g)*KK;
  #pragma unroll
  for (int k = 0; k < KK; k += 4)
    *(float4*)(po + k) = make_float4(acc[k], acc[k+1], acc[k+2], acc[k+3]);
  part_ssq[(size_t)dc*NFR + g] = ssq;
}

// ---------------------------------------------------------------------------
// K1b: reduce the 8 d-chunk partials, per-frame L2 norm, softmax, mask.
// one thread per frame.
// ---------------------------------------------------------------------------
__global__ __launch_bounds__(256) void k_softmax(const int* __restrict__ lengths,
    const float* __restrict__ part_dots, const float* __restrict__ part_ssq,
    float* __restrict__ aw, float* __restrict__ invn) {
  const int g = blockIdx.x*256 + threadIdx.x;
  const int b = g >> 7, m = g & (MM-1);

  float s[KK];
  #pragma unroll
  for (int k = 0; k < KK; ++k) s[k] = 0.f;
  float ssq = 0.f;
  for (int c = 0; c < 8; ++c) {
    const float* p = part_dots + ((size_t)c*NFR + g)*KK;
    #pragma unroll
    for (int k = 0; k < KK; k += 4) {
      float4 v = *(const float4*)(p + k);
      s[k] += v.x; s[k+1] += v.y; s[k+2] += v.z; s[k+3] += v.w;
    }
    ssq += part_ssq[(size_t)c*NFR + g];
  }

  float inv = 1.f / fmaxf(sqrtf(ssq), 1e-12f);
  invn[g] = inv;
  const bool valid = m < lengths[b];

  float mx = -1e30f;
  #pragma unroll
  for (int k = 0; k < KK; ++k) { s[k] *= inv; mx = fmaxf(mx, s[k]); }
  float se = 0.f;
  #pragma unroll
  for (int k = 0; k < KK; ++k) { s[k] = __expf(s[k] - mx); se += s[k]; }
  float r = valid ? (1.f / se) : 0.f;

  float* ao = aw + (size_t)g*KK;
  #pragma unroll
  for (int k = 0; k < KK; k += 4)
    *(float4*)(ao + k) = make_float4(s[k]*r, s[k+1]*r, s[k+2]*r, s[k+3]*r);
}

// ---------------------------------------------------------------------------
// K2: per-b rank-K accumulation  ax[k,d] = sum_m a[m,k]*xn[m,d], fused with
// avgpool and local asum. thread owns 2 d-columns; a-row loads are
// wave-uniform (scalar operands to v_fmac). Writes raw vlad into out region.
// grid (4 d-chunks, 64 b) x 256 threads.
// ---------------------------------------------------------------------------
__global__ __launch_bounds__(256) void k_vlad(const float* __restrict__ x,
    const int* __restrict__ lengths, const float* __restrict__ Cc,
    const float* __restrict__ aw, const float* __restrict__ invn,
    float* __restrict__ out, float* __restrict__ ssq_part) {
  const int t  = threadIdx.x;
  const int dc = blockIdx.x;     // 0..3
  const int b  = blockIdx.y;     // 0..63
  const int d  = dc*512 + t*2;
  const int len = lengths[b];

  __shared__ float asred[8][KK];
  __shared__ float ssql[4][KK];

  { // asum prologue: asum[k] = sum_m a[b,m,k]
    int k = t & 31, sl = t >> 5;
    float p = 0.f;
    for (int m = sl; m < len; m += 8)
      p += aw[(size_t)(b*MM + m)*KK + k];
    asred[sl][k] = p;
  }
  __syncthreads();

  float acc0[KK], acc1[KK];
  #pragma unroll
  for (int k = 0; k < KK; ++k) { acc0[k] = 0.f; acc1[k] = 0.f; }
  float avg0 = 0.f, avg1 = 0.f;

  const float* xrow = x + (size_t)(b*MM)*DDIM + d;
  #pragma unroll 2
  for (int m = 0; m < len; ++m) {
    const float* ap = aw + (size_t)(b*MM + m)*KK;   // wave-uniform
    float inv = invn[b*MM + m];                      // wave-uniform
    float2 xv = *(const float2*)(xrow + (size_t)m*DDIM);
    avg0 += xv.x; avg1 += xv.y;
    float xn0 = xv.x*inv, xn1 = xv.y*inv;
    #pragma unroll
    for (int k = 0; k < KK; ++k) {
      float a = ap[k];
      acc0[k] = fmaf(a, xn0, acc0[k]);
      acc1[k] = fmaf(a, xn1, acc1[k]);
    }
  }

  float rlen = 1.f / (float)len;
  float* orow = out + (size_t)b*OUTROW;
  *(float2*)(orow + d) = make_float2(avg0*rlen, avg1*rlen);

  const int lane = t & 63, w = t >> 6;
  #pragma unroll
  for (int k = 0; k < KK; ++k) {
    float asum = 0.f;
    #pragma unroll
    for (int sl = 0; sl < 8; ++sl) asum += asred[sl][k];
    float2 cv = *(const float2*)(Cc + (size_t)k*DDIM + d);
    float v0 = acc0[k] - asum*cv.x;
    float v1 = acc1[k] - asum*cv.y;
    *(float2*)(orow + DDIM + (size_t)k*DDIM + d) = make_float2(v0, v1);
    float sq = v0*v0 + v1*v1;
    #pragma unroll
    for (int off = 32; off > 0; off >>= 1)
      sq += __shfl_down(sq, off, 64);
    if (lane == 0) ssql[w][k] = sq;
  }
  __syncthreads();
  if (t < KK) {
    float sv = ssql[0][t] + ssql[1][t] + ssql[2][t] + ssql[3][t];
    ssq_part[((size_t)dc*BB + b)*KK + t] = sv;
  }
}

// ---------------------------------------------------------------------------
// K3: intra-cluster + global L2 normalization, in-place scale of out region.
// grid (2 d-chunks, 64 b) x 256 threads, float4 per thread.
// ---------------------------------------------------------------------------
__global__ __launch_bounds__(256) void k_norm(const float* __restrict__ ssq_part,
    float* __restrict__ out) {
  const int t  = threadIdx.x;
  const int dc = blockIdx.x;   // 0..1
  const int b  = blockIdx.y;
  const int d  = dc*1024 + t*4;

  float sk[KK];
  #pragma unroll
  for (int k = 0; k < KK; ++k) sk[k] = 0.f;
  for (int c = 0; c < 4; ++c) {
    const float* p = ssq_part + ((size_t)c*BB + b)*KK;
    #pragma unroll
    for (int k = 0; k < KK; ++k) sk[k] += p[k];
  }

  float invk[KK];
  float gss = 0.f;
  #pragma unroll
  for (int k = 0; k < KK; ++k) {
    float nk = sqrtf(sk[k]);
    float iv = 1.f / fmaxf(nk, 1e-12f);
    invk[k] = iv;
    float nn = nk * iv;
    gss += nn*nn;
  }
  float ginv = 1.f / fmaxf(sqrtf(gss), 1e-12f);

  float* orow = out + (size_t)b*OUTROW + DDIM;
  #pragma unroll
  for (int k = 0; k < KK; ++k) {
    float sc = invk[k] * ginv;
    float4* p = (float4*)(orow + (size_t)k*DDIM + d);
    float4 v = *p;
    v.x *= sc; v.y *= sc; v.z *= sc; v.w *= sc;
    *p = v;
  }
}

// ---------------------------------------------------------------------------
extern "C" void kernel_launch(void* const* d_in, const int* in_sizes, int n_in,
                              void* d_out, int out_size, void* d_ws, size_t ws_size,
                              hipStream_t stream) {
  const float* x       = (const float*)d_in[0];
  const int*   lengths = (const int*)d_in[1];
  const float* W       = (const float*)d_in[2];
  const float* C       = (const float*)d_in[3];
  float* out = (float*)d_out;

  float* ws        = (float*)d_ws;
  float* part_dots = ws;                        // 8*8192*32 = 2,097,152 floats
  float* part_ssq  = part_dots + 8*NFR*KK;      // 8*8192    =    65,536
  float* aw        = part_ssq  + 8*NFR;         // 8192*32   =   262,144
  float* invn      = aw        + (size_t)NFR*KK;// 8192
  float* ssq_part  = invn      + NFR;           // 4*64*32   =     8,192
  // total ~9.6 MB of ws

  k_dots   <<<dim3(32, 8), 256, 0, stream>>>(x, lengths, W, part_dots, part_ssq);
  k_softmax<<<dim3(32),    256, 0, stream>>>(lengths, part_dots, part_ssq, aw, invn);
  k_vlad   <<<dim3(4, 64), 256, 0, stream>>>(x, lengths, C, aw, invn, out, ssq_part);
  k_norm   <<<dim3(2, 64), 256, 0, stream>>>(ssq_part, out);
}

// Round 2
// 214.850 us; speedup vs baseline: 1.0932x; 1.0932x over previous
//
#include <hip/hip_runtime.h>
#include <math.h>

#define BB 64
#define MM 128
#define DDIM 2048
#define KK 32
#define NFR (BB*MM)              // 8192
#define OUTROW (DDIM + KK*DDIM)  // 67584

// ---------------------------------------------------------------------------
// K1: partial logits + partial ssq per frame over a d-chunk of width dcw.
// grid (32 frame-groups, ndc d-chunks) x 256 threads.
// x staged via LDS TRANSPOSED: xs[d][frame] (stride 257 -> (d+fr)%32 banks,
// conflict-free writes AND reads). Compute: xv[32] register-resident, k-outer
// loop so W reads are contiguous wave-uniform (wide s_load), 32 FMA per row.
// ---------------------------------------------------------------------------
__global__ __launch_bounds__(256) void k_dots(const float* __restrict__ x,
        const int* __restrict__ lengths, const float* __restrict__ W,
        float* __restrict__ part_dots, float* __restrict__ part_ssq, int dcw) {
  __shared__ float xs[32][257];   // [d][frame]
  const int t  = threadIdx.x;
  const int fg = blockIdx.x;      // 0..31  (256 frames each)
  const int dc = blockIdx.y;      // 0..ndc-1
  const int g0 = fg * 256;
  const int d0 = dc * dcw;
  const int sN = dcw >> 5;

  const int fr_st = t >> 3;       // staging frame sub-index 0..31
  const int dq    = t & 7;        // staging float4 column 0..7

  bool va[8];
  #pragma unroll
  for (int i = 0; i < 8; ++i) {
    int g = g0 + i*32 + fr_st;
    va[i] = (g & (MM-1)) < lengths[g >> 7];
  }

  float acc[KK];
  #pragma unroll
  for (int k = 0; k < KK; ++k) acc[k] = 0.f;
  float ssq = 0.f;

  for (int s = 0; s < sN; ++s) {
    const int dbase = d0 + s*32;
    #pragma unroll
    for (int i = 0; i < 8; ++i) {
      int fr = i*32 + fr_st;
      int g  = g0 + fr;
      float4 v = make_float4(0.f, 0.f, 0.f, 0.f);
      if (va[i]) v = *(const float4*)(x + (size_t)g*DDIM + dbase + dq*4);
      xs[dq*4+0][fr] = v.x; xs[dq*4+1][fr] = v.y;
      xs[dq*4+2][fr] = v.z; xs[dq*4+3][fr] = v.w;
    }
    __syncthreads();

    float xv[32];
    #pragma unroll
    for (int dd = 0; dd < 32; ++dd) {
      xv[dd] = xs[dd][t];
      ssq = fmaf(xv[dd], xv[dd], ssq);
    }

    const float* wp = W + dbase;   // wave-uniform
    #pragma unroll 4
    for (int k = 0; k < KK; ++k) {
      const float* wr = wp + (size_t)k*DDIM;  // contiguous 32 floats, scalar
      float a = acc[k];
      #pragma unroll
      for (int dd = 0; dd < 32; ++dd) a = fmaf(wr[dd], xv[dd], a);
      acc[k] = a;
    }
    __syncthreads();
  }

  const int g = g0 + t;
  float* po = part_dots + ((size_t)dc*NFR + g)*KK;
  #pragma unroll
  for (int k = 0; k < KK; k += 4)
    *(float4*)(po + k) = make_float4(acc[k], acc[k+1], acc[k+2], acc[k+3]);
  part_ssq[(size_t)dc*NFR + g] = ssq;
}

// ---------------------------------------------------------------------------
// K1b: reduce ndc partials, per-frame L2 norm, stable softmax, mask.
// 4 threads per frame (quad owns 8 clusters each), quad butterflies for
// ssq / max / sum. grid 128 x 256.
// ---------------------------------------------------------------------------
__global__ __launch_bounds__(256) void k_softmax(const int* __restrict__ lengths,
    const float* __restrict__ part_dots, const float* __restrict__ part_ssq,
    float* __restrict__ aw, float* __restrict__ invn, int ndc) {
  const int t  = threadIdx.x;
  const int gt = blockIdx.x*256 + t;
  const int g  = gt >> 2;          // frame 0..8191
  const int q  = t & 3;            // quad lane
  const int b  = g >> 7, m = g & (MM-1);

  float s[8];
  #pragma unroll
  for (int i = 0; i < 8; ++i) s[i] = 0.f;
  for (int c = 0; c < ndc; ++c) {
    const float* p = part_dots + ((size_t)c*NFR + g)*KK + q*8;
    float4 v0 = *(const float4*)p;
    float4 v1 = *(const float4*)(p + 4);
    s[0]+=v0.x; s[1]+=v0.y; s[2]+=v0.z; s[3]+=v0.w;
    s[4]+=v1.x; s[5]+=v1.y; s[6]+=v1.z; s[7]+=v1.w;
  }
  const int cq = ndc >> 2;
  float ssq = 0.f;
  for (int c = q*cq; c < (q+1)*cq; ++c) ssq += part_ssq[(size_t)c*NFR + g];
  ssq += __shfl_xor(ssq, 1, 64); ssq += __shfl_xor(ssq, 2, 64);

  float inv = 1.f / fmaxf(sqrtf(ssq), 1e-12f);
  if (q == 0) invn[g] = inv;

  float mx = -1e30f;
  #pragma unroll
  for (int i = 0; i < 8; ++i) { s[i] *= inv; mx = fmaxf(mx, s[i]); }
  mx = fmaxf(mx, __shfl_xor(mx, 1, 64));
  mx = fmaxf(mx, __shfl_xor(mx, 2, 64));
  float se = 0.f;
  #pragma unroll
  for (int i = 0; i < 8; ++i) { s[i] = __expf(s[i] - mx); se += s[i]; }
  se += __shfl_xor(se, 1, 64); se += __shfl_xor(se, 2, 64);

  const bool valid = m < lengths[b];
  float r = valid ? (1.f / se) : 0.f;
  float* ao = aw + (size_t)g*KK + q*8;
  *(float4*)ao       = make_float4(s[0]*r, s[1]*r, s[2]*r, s[3]*r);
  *(float4*)(ao + 4) = make_float4(s[4]*r, s[5]*r, s[6]*r, s[7]*r);
}

// ---------------------------------------------------------------------------
// K2: vlad accumulation, thread = 1 d-column, m-unrolled x2 for ILP.
// grid (8 d-chunks, 64 b) x 256. Fuses avgpool + asum + raw vlad write +
// per-cluster ssq reduction.
// ---------------------------------------------------------------------------
__global__ __launch_bounds__(256) void k_vlad(const float* __restrict__ x,
    const int* __restrict__ lengths, const float* __restrict__ Cc,
    const float* __restrict__ aw, const float* __restrict__ invn,
    float* __restrict__ out, float* __restrict__ ssq_part) {
  const int t  = threadIdx.x;
  const int dc = blockIdx.x;     // 0..7
  const int b  = blockIdx.y;     // 0..63
  const int d  = dc*256 + t;
  const int len = lengths[b];

  __shared__ float asred[8][KK];
  __shared__ float ssql[4][KK];

  { // asum[k] = sum_m a[b,m,k]
    int k = t & 31, sl = t >> 5;
    float p = 0.f;
    for (int m = sl; m < len; m += 8)
      p += aw[(size_t)(b*MM + m)*KK + k];
    asred[sl][k] = p;
  }
  __syncthreads();

  float acc[KK];
  #pragma unroll
  for (int k = 0; k < KK; ++k) acc[k] = 0.f;
  float avg = 0.f;

  const float* xcol = x + (size_t)b*MM*DDIM + d;
  int m = 0;
  for (; m + 1 < len; m += 2) {
    const float* a0 = aw + (size_t)(b*MM + m)*KK;   // wave-uniform
    const float* a1 = a0 + KK;
    float i0 = invn[b*MM + m], i1 = invn[b*MM + m + 1];
    float x0 = xcol[(size_t)m*DDIM];
    float x1 = xcol[(size_t)(m+1)*DDIM];
    avg += x0 + x1;
    float n0 = x0*i0, n1 = x1*i1;
    #pragma unroll
    for (int k = 0; k < KK; ++k)
      acc[k] = fmaf(a1[k], n1, fmaf(a0[k], n0, acc[k]));
  }
  if (m < len) {
    const float* a0 = aw + (size_t)(b*MM + m)*KK;
    float i0 = invn[b*MM + m];
    float x0 = xcol[(size_t)m*DDIM];
    avg += x0;
    float n0 = x0*i0;
    #pragma unroll
    for (int k = 0; k < KK; ++k) acc[k] = fmaf(a0[k], n0, acc[k]);
  }

  float* orow = out + (size_t)b*OUTROW;
  orow[d] = avg / (float)len;

  const int lane = t & 63, w = t >> 6;
  #pragma unroll
  for (int k = 0; k < KK; ++k) {
    float asum = 0.f;
    #pragma unroll
    for (int sl = 0; sl < 8; ++sl) asum += asred[sl][k];
    float v = acc[k] - asum * Cc[(size_t)k*DDIM + d];
    orow[DDIM + (size_t)k*DDIM + d] = v;
    float sq = v*v;
    #pragma unroll
    for (int off = 32; off > 0; off >>= 1)
      sq += __shfl_down(sq, off, 64);
    if (lane == 0) ssql[w][k] = sq;
  }
  __syncthreads();
  if (t < KK) {
    ssq_part[((size_t)dc*BB + b)*KK + t] =
        ssql[0][t] + ssql[1][t] + ssql[2][t] + ssql[3][t];
  }
}

// ---------------------------------------------------------------------------
// K3: intra + global L2 normalize, in-place scale. grid (4,64) x 128, float4.
// ---------------------------------------------------------------------------
__global__ __launch_bounds__(128) void k_norm(const float* __restrict__ ssq_part,
    float* __restrict__ out) {
  const int t  = threadIdx.x;
  const int dc = blockIdx.x;   // 0..3
  const int b  = blockIdx.y;
  const int d  = dc*512 + t*4;

  float sk[KK];
  #pragma unroll
  for (int k = 0; k < KK; ++k) sk[k] = 0.f;
  for (int c = 0; c < 8; ++c) {
    const float* p = ssq_part + ((size_t)c*BB + b)*KK;
    #pragma unroll
    for (int k = 0; k < KK; ++k) sk[k] += p[k];
  }

  float invk[KK];
  float gss = 0.f;
  #pragma unroll
  for (int k = 0; k < KK; ++k) {
    float nk = sqrtf(sk[k]);
    float iv = 1.f / fmaxf(nk, 1e-12f);
    invk[k] = iv;
    float nn = nk * iv;
    gss += nn*nn;
  }
  float ginv = 1.f / fmaxf(sqrtf(gss), 1e-12f);

  float* orow = out + (size_t)b*OUTROW + DDIM;
  #pragma unroll
  for (int k = 0; k < KK; ++k) {
    float sc = invk[k] * ginv;
    float4* p = (float4*)(orow + (size_t)k*DDIM + d);
    float4 v = *p;
    v.x *= sc; v.y *= sc; v.z *= sc; v.w *= sc;
    *p = v;
  }
}

// ---------------------------------------------------------------------------
extern "C" void kernel_launch(void* const* d_in, const int* in_sizes, int n_in,
                              void* d_out, int out_size, void* d_ws, size_t ws_size,
                              hipStream_t stream) {
  const float* x       = (const float*)d_in[0];
  const int*   lengths = (const int*)d_in[1];
  const float* W       = (const float*)d_in[2];
  const float* C       = (const float*)d_in[3];
  float* out = (float*)d_out;

  // pick finest d-split that fits ws (ws_size is constant across calls, so
  // this host-side selection is deterministic / graph-safe)
  const size_t fixed = ((size_t)NFR*KK + NFR + 8*(size_t)BB*KK) * 4;
  const size_t per   = ((size_t)NFR*KK + NFR) * 4;   // one d-chunk of partials
  int ndc;
  if      (ws_size >= fixed + 32*per) ndc = 32;
  else if (ws_size >= fixed + 16*per) ndc = 16;
  else                                 ndc = 8;
  const int dcw = DDIM / ndc;

  float* ws        = (float*)d_ws;
  float* part_dots = ws;                                  // ndc*NFR*KK
  float* part_ssq  = part_dots + (size_t)ndc*NFR*KK;      // ndc*NFR
  float* aw        = part_ssq  + (size_t)ndc*NFR;         // NFR*KK
  float* invn      = aw        + (size_t)NFR*KK;          // NFR
  float* ssq_part  = invn      + NFR;                     // 8*BB*KK

  k_dots   <<<dim3(32, ndc), 256, 0, stream>>>(x, lengths, W, part_dots, part_ssq, dcw);
  k_softmax<<<dim3(128),     256, 0, stream>>>(lengths, part_dots, part_ssq, aw, invn, ndc);
  k_vlad   <<<dim3(8, 64),   256, 0, stream>>>(x, lengths, C, aw, invn, out, ssq_part);
  k_norm   <<<dim3(4, 64),   128, 0, stream>>>(ssq_part, out);
}